// Round 1
// baseline (452.129 us; speedup 1.0000x reference)
//
#include <hip/hip_runtime.h>
#include <hip/hip_bf16.h>

// ---------------- problem constants (match setup_inputs) ----------------
#define T_TOK 4096
#define H_DIM 1024
#define E_NUM 8
#define I_DIM 3584
#define NPAIR (T_TOK * 2)   // top_k = 2
#define MAX_RT 72           // worst-case total row tiles: 8192/128 + 7 experts

#define BM 128
#define BN 128
#define BK 64
#define LDSS 72             // BK + 8 pad (16B) -> 2-way LDS conflicts only

typedef __attribute__((ext_vector_type(8))) short bf16x8;
typedef __attribute__((ext_vector_type(4))) float f32x4;
typedef __attribute__((ext_vector_type(8))) unsigned short ushort8_t;
typedef __attribute__((ext_vector_type(4))) unsigned short ushort4_t;

// RNE fp32 -> bf16 (matches numpy rounding; inputs finite)
__device__ __forceinline__ unsigned short f2bf(float x) {
  unsigned int u = __float_as_uint(x);
  unsigned int r = (u + 0x7FFFu + ((u >> 16) & 1u)) >> 16;
  return (unsigned short)r;
}

// ---------------- transpose + fp32->bf16 convert ----------------
// src: [E][R][C] fp32  ->  dst: [E][C][R] bf16.  grid (C/64, R/64, E), 256 thr
__global__ void transpose_cvt(const float* __restrict__ src,
                              unsigned short* __restrict__ dst, int R, int C) {
  __shared__ float tile[64][68];
  const int e = blockIdx.z;
  const int c0 = blockIdx.x * 64, r0 = blockIdx.y * 64;
  const float* s = src + (size_t)e * R * C;
  unsigned short* d = dst + (size_t)e * R * C;
  const int th = threadIdx.x;
  const int tr = th >> 4;          // 0..15
  const int tc = (th & 15) * 4;    // 0..60
#pragma unroll
  for (int rr = 0; rr < 4; ++rr) {
    const int r = rr * 16 + tr;
    float4 v = *reinterpret_cast<const float4*>(s + (size_t)(r0 + r) * C + c0 + tc);
    tile[r][tc] = v.x; tile[r][tc + 1] = v.y; tile[r][tc + 2] = v.z; tile[r][tc + 3] = v.w;
  }
  __syncthreads();
#pragma unroll
  for (int rr = 0; rr < 4; ++rr) {
    const int c = rr * 16 + tr;
    ushort4_t o = { f2bf(tile[tc][c]), f2bf(tile[tc + 1][c]),
                    f2bf(tile[tc + 2][c]), f2bf(tile[tc + 3][c]) };
    *reinterpret_cast<ushort4_t*>(d + (size_t)(c0 + c) * R + r0 + tc) = o;
  }
}

// ---------------- router: logits -> top2 -> renorm weights ----------------
// one wave per token
__global__ void router_kernel(const float* __restrict__ hs, const float* __restrict__ gw,
                              int* __restrict__ eid, float* __restrict__ wgt,
                              int* __restrict__ counts) {
  const int t = blockIdx.x;
  const int l = threadIdx.x;
  float acc[E_NUM];
#pragma unroll
  for (int e = 0; e < E_NUM; ++e) acc[e] = 0.f;
  const float* hrow = hs + (size_t)t * H_DIM;
  for (int h = l; h < H_DIM; h += 64) {
    const float x = hrow[h];
#pragma unroll
    for (int e = 0; e < E_NUM; ++e) acc[e] += x * gw[h * E_NUM + e];
  }
#pragma unroll
  for (int e = 0; e < E_NUM; ++e) {
#pragma unroll
    for (int off = 32; off > 0; off >>= 1) acc[e] += __shfl_down(acc[e], off);
  }
  if (l == 0) {
    int i1 = 0;
#pragma unroll
    for (int e = 1; e < E_NUM; ++e) if (acc[e] > acc[i1]) i1 = e;
    int i2 = (i1 == 0) ? 1 : 0;
#pragma unroll
    for (int e = 0; e < E_NUM; ++e) if (e != i1 && acc[e] > acc[i2]) i2 = e;
    // renormalized top-2 softmax == pairwise softmax of the two logits
    const float e2 = __expf(acc[i2] - acc[i1]);
    const float inv = 1.f / (1.f + e2);
    eid[t * 2] = i1;     wgt[t * 2] = inv;
    eid[t * 2 + 1] = i2; wgt[t * 2 + 1] = e2 * inv;
    atomicAdd(&counts[i1], 1);
    atomicAdd(&counts[i2], 1);
  }
}

__global__ void scan_kernel(const int* __restrict__ counts, int* __restrict__ offsets) {
  if (threadIdx.x == 0) {
    int s = 0;
    for (int e = 0; e < E_NUM; ++e) { offsets[e] = s; s += counts[e]; }
    offsets[E_NUM] = s;
  }
}

__global__ void scatter_kernel(const int* __restrict__ eid, const int* __restrict__ offsets,
                               int* __restrict__ fill, int* __restrict__ rowmap) {
  const int p = blockIdx.x * blockDim.x + threadIdx.x;
  if (p < NPAIR) {
    const int e = eid[p];
    const int pos = atomicAdd(&fill[e], 1);
    rowmap[offsets[e] + pos] = p;
  }
}

// ---------------- grouped GEMM ----------------
// MODE 0: A = gathered hs (fp32 -> bf16 on stage), B = w1t [E][I][H] bf16,
//         C = silu(acc) -> act bf16 [NPAIR][I_DIM] (rows in sorted-pair order)
// MODE 1: A = act bf16, B = w2t [E][H][I] bf16,
//         C = acc * routing_weight, atomicAdd-scatter into out[t][h]
template <int MODE>
__launch_bounds__(256, 2)
__global__ void moe_gemm(const float* __restrict__ hs,
                         const unsigned short* __restrict__ wt,
                         const unsigned short* __restrict__ act_in,
                         unsigned short* __restrict__ act_out,
                         float* __restrict__ out,
                         const int* __restrict__ offsets,
                         const int* __restrict__ rowmap,
                         const float* __restrict__ wgt) {
  constexpr int KD = (MODE == 0) ? H_DIM : I_DIM;

  __shared__ unsigned short Alds[BM][LDSS];
  __shared__ unsigned short Blds[BN][LDSS];
  __shared__ int s_pair[BM];
  __shared__ float s_w[BM];

  const int rt = blockIdx.x, ct = blockIdx.y;
  // flat row-tile -> (expert, local row tile)
  int e = -1, loc_rt = 0;
  {
    int acc_t = 0;
    for (int ee = 0; ee < E_NUM; ++ee) {
      const int c = offsets[ee + 1] - offsets[ee];
      const int nt = (c + BM - 1) >> 7;
      if (rt < acc_t + nt) { e = ee; loc_rt = rt - acc_t; break; }
      acc_t += nt;
    }
  }
  if (e < 0) return;

  const int off_e = offsets[e];
  const int cnt = offsets[e + 1] - off_e;
  const int cnt_local = min(BM, cnt - loc_rt * BM);
  const int r_base = off_e + loc_rt * BM;
  const int th = threadIdx.x;

  if (th < BM) {
    int r = loc_rt * BM + th;
    if (r >= cnt) r = cnt - 1;           // clamp (guarded at store)
    const int p = rowmap[off_e + r];
    s_pair[th] = p;
    s_w[th] = wgt[p];
  }
  __syncthreads();

  const int n0 = ct * BN;
  const unsigned short* wbase = wt + (size_t)e * ((size_t)I_DIM * H_DIM) + (size_t)n0 * KD;

  f32x4 acc[4][4];
#pragma unroll
  for (int m = 0; m < 4; ++m)
#pragma unroll
    for (int n = 0; n < 4; ++n) acc[m][n] = (f32x4){0.f, 0.f, 0.f, 0.f};

  const int lane = th & 63;
  const int wid = th >> 6;
  const int wm = (wid >> 1) * 64;
  const int wn = (wid & 1) * 64;
  const int fr = lane & 15;
  const int fq = lane >> 4;

  for (int k0 = 0; k0 < KD; k0 += BK) {
    // ---- stage A tile [BM][BK] ----
    if (MODE == 0) {
      const int kk = (th & 15) * 4;
#pragma unroll
      for (int rr = 0; rr < 8; ++rr) {
        const int r = rr * 16 + (th >> 4);
        const int tok = s_pair[r] >> 1;
        float4 v = *reinterpret_cast<const float4*>(hs + (size_t)tok * H_DIM + k0 + kk);
        ushort4_t o = { f2bf(v.x), f2bf(v.y), f2bf(v.z), f2bf(v.w) };
        *reinterpret_cast<ushort4_t*>(&Alds[r][kk]) = o;
      }
    } else {
      const int kk = (th & 7) * 8;
#pragma unroll
      for (int rr = 0; rr < 4; ++rr) {
        const int r = rr * 32 + (th >> 3);
        const int rv = (r < cnt_local) ? r : (cnt_local - 1);
        const ushort8_t v = *reinterpret_cast<const ushort8_t*>(
            act_in + (size_t)(r_base + rv) * I_DIM + k0 + kk);
        *reinterpret_cast<ushort8_t*>(&Alds[r][kk]) = v;
      }
    }
    // ---- stage B tile [BN][BK] (already [n][k] bf16) ----
    {
      const int kk = (th & 7) * 8;
#pragma unroll
      for (int rr = 0; rr < 4; ++rr) {
        const int r = rr * 32 + (th >> 3);
        const ushort8_t v = *reinterpret_cast<const ushort8_t*>(
            wbase + (size_t)r * KD + k0 + kk);
        *reinterpret_cast<ushort8_t*>(&Blds[r][kk]) = v;
      }
    }
    __syncthreads();

    bf16x8 af[4][2], bfr[4][2];
#pragma unroll
    for (int m = 0; m < 4; ++m)
#pragma unroll
      for (int kk = 0; kk < 2; ++kk)
        af[m][kk] = *reinterpret_cast<const bf16x8*>(&Alds[wm + m * 16 + fr][kk * 32 + fq * 8]);
#pragma unroll
    for (int n = 0; n < 4; ++n)
#pragma unroll
      for (int kk = 0; kk < 2; ++kk)
        bfr[n][kk] = *reinterpret_cast<const bf16x8*>(&Blds[wn + n * 16 + fr][kk * 32 + fq * 8]);
#pragma unroll
    for (int kk = 0; kk < 2; ++kk)
#pragma unroll
      for (int m = 0; m < 4; ++m)
#pragma unroll
        for (int n = 0; n < 4; ++n)
          acc[m][n] = __builtin_amdgcn_mfma_f32_16x16x32_bf16(af[m][kk], bfr[n][kk], acc[m][n], 0, 0, 0);
    __syncthreads();
  }

  // ---- epilogue ----
#pragma unroll
  for (int m = 0; m < 4; ++m) {
    const int row = wm + m * 16 + fq * 4;
#pragma unroll
    for (int n = 0; n < 4; ++n) {
      const int col = wn + n * 16 + fr;
#pragma unroll
      for (int r = 0; r < 4; ++r) {
        const int rw = row + r;
        if (rw < cnt_local) {
          const float x = acc[m][n][r];
          if (MODE == 0) {
            const float s = x / (1.f + __expf(-x));   // silu
            act_out[(size_t)(r_base + rw) * I_DIM + n0 + col] = f2bf(s);
          } else {
            const int p = s_pair[rw];
            const int tok = p >> 1;
            atomicAdd(out + (size_t)tok * H_DIM + n0 + col, x * s_w[rw]);
          }
        }
      }
    }
  }
}

// ---------------- launch ----------------
extern "C" void kernel_launch(void* const* d_in, const int* in_sizes, int n_in,
                              void* d_out, int out_size, void* d_ws, size_t ws_size,
                              hipStream_t stream) {
  const float* hs = (const float*)d_in[0];
  const float* gw = (const float*)d_in[1];
  const float* w1 = (const float*)d_in[2];
  const float* w2 = (const float*)d_in[3];
  float* out = (float*)d_out;

  char* ws = (char*)d_ws;
  const size_t WMAT = (size_t)E_NUM * I_DIM * H_DIM * 2;   // 58,720,256 B
  unsigned short* w1t = (unsigned short*)ws;                // [E][I][H] bf16
  unsigned short* w2t = (unsigned short*)(ws + WMAT);       // [E][H][I] bf16
  unsigned short* act = (unsigned short*)(ws + 2 * WMAT);   // [NPAIR][I] bf16
  char* small = ws + 3 * WMAT;
  int* eid = (int*)small;                          // NPAIR
  float* wgt = (float*)(small + NPAIR * 4);        // NPAIR
  int* rowmap = (int*)(small + 2 * NPAIR * 4);     // NPAIR
  int* counts = (int*)(small + 3 * NPAIR * 4);     // 8
  int* fill = counts + 8;                          // 8
  int* offsets = counts + 16;                      // 9

  hipMemsetAsync(d_out, 0, (size_t)T_TOK * H_DIM * sizeof(float), stream);
  hipMemsetAsync(counts, 0, 16 * sizeof(int), stream);

  transpose_cvt<<<dim3(I_DIM / 64, H_DIM / 64, E_NUM), 256, 0, stream>>>(w1, w1t, H_DIM, I_DIM);
  transpose_cvt<<<dim3(H_DIM / 64, I_DIM / 64, E_NUM), 256, 0, stream>>>(w2, w2t, I_DIM, H_DIM);

  router_kernel<<<T_TOK, 64, 0, stream>>>(hs, gw, eid, wgt, counts);
  scan_kernel<<<1, 64, 0, stream>>>(counts, offsets);
  scatter_kernel<<<NPAIR / 256, 256, 0, stream>>>(eid, offsets, fill, rowmap);

  moe_gemm<0><<<dim3(MAX_RT, I_DIM / BN), 256, 0, stream>>>(
      hs, w1t, nullptr, act, nullptr, offsets, rowmap, wgt);
  moe_gemm<1><<<dim3(MAX_RT, H_DIM / BN), 256, 0, stream>>>(
      hs, w2t, act, nullptr, out, offsets, rowmap, wgt);
}

// Round 2
// 429.289 us; speedup vs baseline: 1.0532x; 1.0532x over previous
//
#include <hip/hip_runtime.h>
#include <hip/hip_bf16.h>

// ---------------- problem constants (match setup_inputs) ----------------
#define T_TOK 4096
#define H_DIM 1024
#define E_NUM 8
#define I_DIM 3584
#define NPAIR (T_TOK * 2)   // top_k = 2
#define MAX_RT 72           // worst-case total row tiles: 8192/128 + 7 experts

#define BM 128
#define BN 128
#define BK 64

typedef __attribute__((ext_vector_type(8))) short bf16x8;
typedef __attribute__((ext_vector_type(4))) float f32x4;
typedef __attribute__((ext_vector_type(8))) unsigned short ushort8_t;
typedef __attribute__((ext_vector_type(4))) unsigned short ushort4_t;

// RNE fp32 -> bf16
__device__ __forceinline__ unsigned short f2bf(float x) {
  unsigned int u = __float_as_uint(x);
  unsigned int r = (u + 0x7FFFu + ((u >> 16) & 1u)) >> 16;
  return (unsigned short)r;
}

// async 16B global -> LDS (linear dest: wave-uniform base + lane*16)
__device__ __forceinline__ void gload16(const void* g, unsigned short* l) {
  __builtin_amdgcn_global_load_lds(
      (const __attribute__((address_space(1))) void*)g,
      (__attribute__((address_space(3))) void*)l, 16, 0, 0);
}

// ---------------- hs fp32 -> bf16 ----------------
__global__ void cvt_hs(const float* __restrict__ hs, unsigned short* __restrict__ hsb) {
  const int i = (blockIdx.x * 256 + threadIdx.x) * 8;
  float4 a = *reinterpret_cast<const float4*>(hs + i);
  float4 b = *reinterpret_cast<const float4*>(hs + i + 4);
  ushort8_t o = { f2bf(a.x), f2bf(a.y), f2bf(a.z), f2bf(a.w),
                  f2bf(b.x), f2bf(b.y), f2bf(b.z), f2bf(b.w) };
  *reinterpret_cast<ushort8_t*>(hsb + i) = o;
}

// ---------------- transpose + fp32->bf16 convert ----------------
// src: [E][R][C] fp32  ->  dst: [E][C][R] bf16.  grid (C/64, R/64, E), 256 thr
__global__ void transpose_cvt(const float* __restrict__ src,
                              unsigned short* __restrict__ dst, int R, int C) {
  __shared__ float tile[64][68];
  const int e = blockIdx.z;
  const int c0 = blockIdx.x * 64, r0 = blockIdx.y * 64;
  const float* s = src + (size_t)e * R * C;
  unsigned short* d = dst + (size_t)e * R * C;
  const int th = threadIdx.x;
  const int tr = th >> 4;          // 0..15
  const int tc = (th & 15) * 4;    // 0..60
#pragma unroll
  for (int rr = 0; rr < 4; ++rr) {
    const int r = rr * 16 + tr;
    float4 v = *reinterpret_cast<const float4*>(s + (size_t)(r0 + r) * C + c0 + tc);
    tile[r][tc] = v.x; tile[r][tc + 1] = v.y; tile[r][tc + 2] = v.z; tile[r][tc + 3] = v.w;
  }
  __syncthreads();
#pragma unroll
  for (int rr = 0; rr < 4; ++rr) {
    const int c = rr * 16 + tr;
    ushort4_t o = { f2bf(tile[tc][c]), f2bf(tile[tc + 1][c]),
                    f2bf(tile[tc + 2][c]), f2bf(tile[tc + 3][c]) };
    *reinterpret_cast<ushort4_t*>(d + (size_t)(c0 + c) * R + r0 + tc) = o;
  }
}

// ---------------- router: logits -> top2 -> renorm weights ----------------
__global__ void router_kernel(const float* __restrict__ hs, const float* __restrict__ gw,
                              int* __restrict__ eid, float* __restrict__ wgt,
                              int* __restrict__ counts) {
  const int t = blockIdx.x;
  const int l = threadIdx.x;
  float acc[E_NUM];
#pragma unroll
  for (int e = 0; e < E_NUM; ++e) acc[e] = 0.f;
  const float* hrow = hs + (size_t)t * H_DIM;
  for (int h = l; h < H_DIM; h += 64) {
    const float x = hrow[h];
#pragma unroll
    for (int e = 0; e < E_NUM; ++e) acc[e] += x * gw[h * E_NUM + e];
  }
#pragma unroll
  for (int e = 0; e < E_NUM; ++e) {
#pragma unroll
    for (int off = 32; off > 0; off >>= 1) acc[e] += __shfl_down(acc[e], off);
  }
  if (l == 0) {
    int i1 = 0;
#pragma unroll
    for (int e = 1; e < E_NUM; ++e) if (acc[e] > acc[i1]) i1 = e;
    int i2 = (i1 == 0) ? 1 : 0;
#pragma unroll
    for (int e = 0; e < E_NUM; ++e) if (e != i1 && acc[e] > acc[i2]) i2 = e;
    const float e2 = __expf(acc[i2] - acc[i1]);
    const float inv = 1.f / (1.f + e2);
    eid[t * 2] = i1;     wgt[t * 2] = inv;
    eid[t * 2 + 1] = i2; wgt[t * 2 + 1] = e2 * inv;
    atomicAdd(&counts[i1], 1);
    atomicAdd(&counts[i2], 1);
  }
}

__global__ void scan_kernel(const int* __restrict__ counts, int* __restrict__ offsets) {
  if (threadIdx.x == 0) {
    int s = 0;
    for (int e = 0; e < E_NUM; ++e) { offsets[e] = s; s += counts[e]; }
    offsets[E_NUM] = s;
  }
}

__global__ void scatter_kernel(const int* __restrict__ eid, const int* __restrict__ offsets,
                               int* __restrict__ fill, int* __restrict__ rowmap) {
  const int p = blockIdx.x * blockDim.x + threadIdx.x;
  if (p < NPAIR) {
    const int e = eid[p];
    const int pos = atomicAdd(&fill[e], 1);
    rowmap[offsets[e] + pos] = p;
  }
}

// ---------------- grouped GEMM (m97 structure: global_load_lds + swizzle) ----
// MODE 0: A = gathered hs bf16, B = w1t [E][I][H] bf16, C = silu -> act bf16
// MODE 1: A = act bf16, B = w2t [E][H][I] bf16, C -> atomicAdd out * wgt
template <int MODE>
__launch_bounds__(256, 3)
__global__ void moe_gemm(const unsigned short* __restrict__ hsb,
                         const unsigned short* __restrict__ wt,
                         const unsigned short* __restrict__ act_in,
                         unsigned short* __restrict__ act_out,
                         float* __restrict__ out,
                         const int* __restrict__ offsets,
                         const int* __restrict__ rowmap,
                         const float* __restrict__ wgt) {
  constexpr int KD = (MODE == 0) ? H_DIM : I_DIM;

  __shared__ unsigned short As[BM * BK];
  __shared__ unsigned short Bs[BN * BK];
  __shared__ int s_pair[BM];
  __shared__ float s_w[BM];

  const int rt = blockIdx.x, ct = blockIdx.y;
  int e = -1, loc_rt = 0;
  {
    int acc_t = 0;
    for (int ee = 0; ee < E_NUM; ++ee) {
      const int c = offsets[ee + 1] - offsets[ee];
      const int nt = (c + BM - 1) >> 7;
      if (rt < acc_t + nt) { e = ee; loc_rt = rt - acc_t; break; }
      acc_t += nt;
    }
  }
  if (e < 0) return;

  const int off_e = offsets[e];
  const int cnt = offsets[e + 1] - off_e;
  const int cnt_local = min(BM, cnt - loc_rt * BM);
  const int r_base = off_e + loc_rt * BM;
  const int th = threadIdx.x;
  const int lane = th & 63, wid = th >> 6;

  if (MODE == 1 && th < BM) {
    int r = loc_rt * BM + th;
    if (r >= cnt) r = cnt - 1;
    const int p = rowmap[off_e + r];
    s_pair[th] = p;
    s_w[th] = wgt[p];
  }

  const int n0 = ct * BN;
  const unsigned short* wbase = wt + (size_t)e * ((size_t)I_DIM * H_DIM) + (size_t)n0 * KD;

  // ---- staging geometry: lane covers (row = i*32 + wid*8 + lane/8, chunk = lane%8)
  // LDS dest is linear; source chunk pre-swizzled: cg = (lane&7) ^ (row&7)
  const int srow = lane >> 3;            // 0..7 (row parity within 8-row group)
  const int cg = (lane & 7) ^ srow;      // swizzled source 16B-chunk index
  const char* aptr[4];
  const char* bptr[4];
#pragma unroll
  for (int i = 0; i < 4; ++i) {
    const int r = i * 32 + wid * 8 + srow;
    const int rr = (r < cnt_local) ? r : (cnt_local - 1);
    if (MODE == 0) {
      const int tok = rowmap[off_e + loc_rt * BM + rr] >> 1;
      aptr[i] = (const char*)(hsb + (size_t)tok * H_DIM) + cg * 16;
    } else {
      aptr[i] = (const char*)(act_in + (size_t)(r_base + rr) * I_DIM) + cg * 16;
    }
    bptr[i] = (const char*)(wbase + (size_t)r * KD) + cg * 16;
  }
  unsigned short* dstA[4];
  unsigned short* dstB[4];
#pragma unroll
  for (int i = 0; i < 4; ++i) {
    dstA[i] = &As[(i * 32 + wid * 8) * BK];   // wave-uniform
    dstB[i] = &Bs[(i * 32 + wid * 8) * BK];
  }

  f32x4 acc[4][4];
#pragma unroll
  for (int m = 0; m < 4; ++m)
#pragma unroll
    for (int n = 0; n < 4; ++n) acc[m][n] = (f32x4){0.f, 0.f, 0.f, 0.f};

  const int wm = (wid >> 1) * 64;
  const int wn = (wid & 1) * 64;
  const int fr = lane & 15;
  const int fq = lane >> 4;
  const int sxor = fr & 7;

  for (int k0 = 0; k0 < KD; k0 += BK) {
    const int kb = k0 * 2;
#pragma unroll
    for (int i = 0; i < 4; ++i) gload16(aptr[i] + kb, dstA[i]);
#pragma unroll
    for (int i = 0; i < 4; ++i) gload16(bptr[i] + kb, dstB[i]);
    __syncthreads();   // compiler drains vmcnt before s_barrier

#pragma unroll
    for (int kk = 0; kk < 2; ++kk) {
      bf16x8 af[4], bf[4];
#pragma unroll
      for (int m = 0; m < 4; ++m)
        af[m] = *reinterpret_cast<const bf16x8*>(
            &As[(wm + m * 16 + fr) * BK + ((kk * 4 + fq) ^ sxor) * 8]);
#pragma unroll
      for (int n = 0; n < 4; ++n)
        bf[n] = *reinterpret_cast<const bf16x8*>(
            &Bs[(wn + n * 16 + fr) * BK + ((kk * 4 + fq) ^ sxor) * 8]);
#pragma unroll
      for (int m = 0; m < 4; ++m)
#pragma unroll
        for (int n = 0; n < 4; ++n)
          acc[m][n] = __builtin_amdgcn_mfma_f32_16x16x32_bf16(af[m], bf[n], acc[m][n], 0, 0, 0);
    }
    __syncthreads();
  }

  // ---- epilogue ----
#pragma unroll
  for (int m = 0; m < 4; ++m) {
    const int row = wm + m * 16 + fq * 4;
#pragma unroll
    for (int n = 0; n < 4; ++n) {
      const int col = wn + n * 16 + fr;
#pragma unroll
      for (int r = 0; r < 4; ++r) {
        const int rw = row + r;
        if (rw < cnt_local) {
          const float x = acc[m][n][r];
          if (MODE == 0) {
            const float s = x / (1.f + __expf(-x));   // silu
            act_out[(size_t)(r_base + rw) * I_DIM + n0 + col] = f2bf(s);
          } else {
            const int p = s_pair[rw];
            const int tok = p >> 1;
            atomicAdd(out + (size_t)tok * H_DIM + n0 + col, x * s_w[rw]);
          }
        }
      }
    }
  }
}

// ---------------- launch ----------------
extern "C" void kernel_launch(void* const* d_in, const int* in_sizes, int n_in,
                              void* d_out, int out_size, void* d_ws, size_t ws_size,
                              hipStream_t stream) {
  const float* hs = (const float*)d_in[0];
  const float* gw = (const float*)d_in[1];
  const float* w1 = (const float*)d_in[2];
  const float* w2 = (const float*)d_in[3];
  float* out = (float*)d_out;

  char* ws = (char*)d_ws;
  const size_t WMAT = (size_t)E_NUM * I_DIM * H_DIM * 2;   // 58,720,256 B
  unsigned short* w1t = (unsigned short*)ws;                // [E][I][H] bf16
  unsigned short* w2t = (unsigned short*)(ws + WMAT);       // [E][H][I] bf16
  unsigned short* act = (unsigned short*)(ws + 2 * WMAT);   // [NPAIR][I] bf16
  unsigned short* hsb = (unsigned short*)(ws + 3 * WMAT);   // [T][H] bf16
  char* small = ws + 3 * WMAT + (size_t)T_TOK * H_DIM * 2;
  int* eid = (int*)small;                          // NPAIR
  float* wgt = (float*)(small + NPAIR * 4);        // NPAIR
  int* rowmap = (int*)(small + 2 * NPAIR * 4);     // NPAIR
  int* counts = (int*)(small + 3 * NPAIR * 4);     // 8
  int* fill = counts + 8;                          // 8
  int* offsets = counts + 16;                      // 9

  hipMemsetAsync(d_out, 0, (size_t)T_TOK * H_DIM * sizeof(float), stream);
  hipMemsetAsync(counts, 0, 16 * sizeof(int), stream);

  transpose_cvt<<<dim3(I_DIM / 64, H_DIM / 64, E_NUM), 256, 0, stream>>>(w1, w1t, H_DIM, I_DIM);
  transpose_cvt<<<dim3(H_DIM / 64, I_DIM / 64, E_NUM), 256, 0, stream>>>(w2, w2t, I_DIM, H_DIM);
  cvt_hs<<<(T_TOK * H_DIM) / 2048, 256, 0, stream>>>(hs, hsb);

  router_kernel<<<T_TOK, 64, 0, stream>>>(hs, gw, eid, wgt, counts);
  scan_kernel<<<1, 64, 0, stream>>>(counts, offsets);
  scatter_kernel<<<NPAIR / 256, 256, 0, stream>>>(eid, offsets, fill, rowmap);

  moe_gemm<0><<<dim3(MAX_RT, I_DIM / BN), 256, 0, stream>>>(
      hsb, w1t, nullptr, act, nullptr, offsets, rowmap, wgt);
  moe_gemm<1><<<dim3(MAX_RT, H_DIM / BN), 256, 0, stream>>>(
      hsb, w2t, act, nullptr, out, offsets, rowmap, wgt);
}